// Round 13
// baseline (1883.005 us; speedup 1.0000x reference)
//
#include <hip/hip_runtime.h>
#include <hip/hip_bf16.h>
#include <cstddef>
#include <cstdint>

#define T_TOK 1024
#define HDIM  2048
#define NEXP  64
#define IDIM  768
#define TOPK  8

using f32x4 = __attribute__((ext_vector_type(4))) float;
using s16x8 = __attribute__((ext_vector_type(8))) short;

// ---- workspace layout (bytes) ----
static constexpr size_t XBF_OFF = 0;                                   // bf16 X: 4 MiB
static constexpr size_t CNT_OFF = (size_t)T_TOK * HDIM * 2;            // 64 ints
static constexpr size_t OFF_OFF = CNT_OFF + 256;                       // 65 ints
static constexpr size_t QM_OFF  = CNT_OFF + 768;                      // nrg
static constexpr size_t RGL_OFF = CNT_OFF + 1024;                      // rowgroup list
static constexpr size_t TOK_OFF = CNT_OFF + 4096;                      // 64*1024 ints
static constexpr size_t WT_OFF  = TOK_OFF + (size_t)NEXP * T_TOK * 4;  // 64*1024 floats
static constexpr size_t G_OFF   = WT_OFF  + (size_t)NEXP * T_TOK * 4;  // 8192*768 bf16 (g -> h)
static constexpr size_t U_OFF   = G_OFF   + (size_t)8192 * IDIM * 2;   // 8192*768 bf16 (u)

__device__ __forceinline__ short f2bf(float f) {
  union { __hip_bfloat16 b; short s; } u;
  u.b = __float2bfloat16(f);
  return u.s;
}
__device__ __forceinline__ uint32_t pk2(float lo, float hi) {
  return ((uint32_t)(uint16_t)f2bf(hi) << 16) | (uint16_t)f2bf(lo);
}
__device__ __forceinline__ void barrier_raw() {
  asm volatile("" ::: "memory");
  __builtin_amdgcn_s_barrier();
  asm volatile("" ::: "memory");
}
#define WAIT_LGKM0() asm volatile("s_waitcnt lgkmcnt(0)" ::: "memory")

// ---------------- router (+ fused fp32->bf16 convert of X) ----------------
__global__ __launch_bounds__(256) void router_kernel(
    const float* __restrict__ X, const float* __restrict__ GW,
    __hip_bfloat16* __restrict__ Xb,
    int* __restrict__ cnt, int* __restrict__ tokl, float* __restrict__ wtl) {
  __shared__ float xs[HDIM];
  __shared__ float lg[NEXP];
  const int t = blockIdx.x;
  const int tid = threadIdx.x;
  const f32x4* xr = (const f32x4*)(X + (size_t)t * HDIM);
#pragma unroll
  for (int i = 0; i < 2; ++i) {
    f32x4 v = xr[tid + i * 256];
    *(f32x4*)&xs[(tid + i * 256) * 4] = v;
  }
  __syncthreads();
  {
    union { short h[8]; int4 q; } u;
#pragma unroll
    for (int j = 0; j < 8; ++j) u.h[j] = f2bf(xs[tid * 8 + j]);
    *(int4*)((char*)Xb + ((size_t)t * HDIM + tid * 8) * 2) = u.q;
  }
  const int wid = tid >> 6, lane = tid & 63;
  for (int ee = 0; ee < 16; ++ee) {
    const int e = wid * 16 + ee;
    const float* g = GW + (size_t)e * HDIM;
    float acc = 0.f;
    for (int i = lane; i < HDIM; i += 64) acc += xs[i] * g[i];
#pragma unroll
    for (int s = 32; s; s >>= 1) acc += __shfl_xor(acc, s);
    if (lane == 0) lg[e] = acc;
  }
  __syncthreads();
  if (tid < 64) {
    const float v = lg[tid];
    float m = v;
#pragma unroll
    for (int s = 32; s; s >>= 1) m = fmaxf(m, __shfl_xor(m, s));
    const float p = expf(v - m);
    float den = p;
#pragma unroll
    for (int s = 32; s; s >>= 1) den += __shfl_xor(den, s);
    float work = p / den;
    float my_v = 0.f; int my_e = 0;
    float topsum = 0.f;
#pragma unroll
    for (int k = 0; k < TOPK; ++k) {
      float mv = work;
#pragma unroll
      for (int s = 32; s; s >>= 1) mv = fmaxf(mv, __shfl_xor(mv, s));
      unsigned long long ball = __ballot(work == mv);
      const int idx = __ffsll(ball) - 1;   // lowest index on ties (matches lax.top_k)
      topsum += mv;
      if (tid == k) { my_v = mv; my_e = idx; }
      if (tid == idx) work = -1.f;
    }
    if (tid < TOPK) {
      const float w = my_v / topsum;
      const int slot = atomicAdd(&cnt[my_e], 1);
      tokl[my_e * T_TOK + slot] = t;
      wtl[my_e * T_TOK + slot] = w;
    }
  }
}

// ---------------- prefix scan + rowgroup list (BM=192) ----------------
__global__ void scan_kernel(const int* __restrict__ cnt, int* __restrict__ offs,
                            int* __restrict__ rgl, int* __restrict__ qm) {
  if (threadIdx.x == 0) {
    int a = 0, nrg = 0;
    for (int e = 0; e < NEXP; ++e) {
      offs[e] = a;
      const int ne = cnt[e];
      a += ne;
      for (int t = 0; t * 192 < ne; ++t) rgl[nrg++] = (e << 4) | t;
    }
    offs[NEXP] = a;
    qm[2] = nrg;
  }
}

// ======================= unified tile machinery =======================
// 256 thr / 4 waves; tile: A 192rows x 32k bf16 (12KB), B 32k x 256n
// fp32 -> bf16 (16KB). Buffer = 28672B, double-buffered (57344 -> 2
// blocks/CU). B staged as whole 1KB rows (f32x4 x 64 lanes). Wave grid
// 2x2 (wr=wid&1: 96 rows, wc=wid>>1: 128 cols) -> acc[6][8] f32x4.
// A staged one 64B row per thread (tid<192), chunk XOR row&3 swizzle.
#define BUFSZ 28672

#define LOADA_(S)                                          \
    xa0_##S = *(const int4*)pap;                           \
    xa1_##S = *(const int4*)(pap + 8);                     \
    xa2_##S = *(const int4*)(pap + 16);                    \
    xa3_##S = *(const int4*)(pap + 24);                    \
    pap += 32;
#define LOADB_(S, LD)                                      \
    v0_##S = *(const f32x4*)(pbp);                         \
    v1_##S = *(const f32x4*)(pbp + (LD));                  \
    v2_##S = *(const f32x4*)(pbp + 2 * (LD));              \
    v3_##S = *(const f32x4*)(pbp + 3 * (LD));              \
    v4_##S = *(const f32x4*)(pbp + 4 * (LD));              \
    v5_##S = *(const f32x4*)(pbp + 5 * (LD));              \
    v6_##S = *(const f32x4*)(pbp + 6 * (LD));              \
    v7_##S = *(const f32x4*)(pbp + 7 * (LD));              \
    pbp += (size_t)32 * (LD);
#define LOADSET(S, LD) { if (doA) { LOADA_(S) } LOADB_(S, LD) }

#define PKPAIR(dst_, va_, vb_) {                           \
    union { uint32_t u[4]; int4 q; } w_;                   \
    w_.u[0] = pk2(va_[0], vb_[0]);                         \
    w_.u[1] = pk2(va_[1], vb_[1]);                         \
    w_.u[2] = pk2(va_[2], vb_[2]);                         \
    w_.u[3] = pk2(va_[3], vb_[3]);                         \
    *(int4*)(dst_) = w_.q; }

#define WRITESET(S, BUF) {                                 \
    char* base_ = sL + (BUF) * BUFSZ;                      \
    if (doA) {                                             \
      *(int4*)(base_ + adst0) = xa0_##S;                   \
      *(int4*)(base_ + adst1) = xa1_##S;                   \
      *(int4*)(base_ + adst2) = xa2_##S;                   \
      *(int4*)(base_ + adst3) = xa3_##S;                   \
    }                                                      \
    PKPAIR(base_ + bdst,        v0_##S, v1_##S)            \
    PKPAIR(base_ + bdst + 1024, v2_##S, v3_##S)            \
    PKPAIR(base_ + bdst + 2048, v4_##S, v5_##S)            \
    PKPAIR(base_ + bdst + 3072, v6_##S, v7_##S) }

#define STEP(S_L, S_W, RB, WB, LD, DO_LOAD, DO_WRITE) {    \
    if (DO_LOAD) LOADSET(S_L, LD)                          \
    const char* bb_ = sL + (RB) * BUFSZ;                   \
    s16x8 af[6];                                           \
    _Pragma("unroll") for (int mi = 0; mi < 6; ++mi)       \
      af[mi] = *(const s16x8*)(bb_ + aoffs[mi]);           \
    s16x8 bf[8];                                           \
    _Pragma("unroll") for (int nf = 0; nf < 8; ++nf) {     \
      const char* p_ = bb_ + boffs[nf];                    \
      union { uint32_t u[4]; s16x8 v; } w_;                \
      w_.u[0] = *(const uint32_t*)p_;                      \
      w_.u[1] = *(const uint32_t*)(p_ + 1024);             \
      w_.u[2] = *(const uint32_t*)(p_ + 2048);             \
      w_.u[3] = *(const uint32_t*)(p_ + 3072);             \
      bf[nf] = w_.v; }                                     \
    WAIT_LGKM0();                                          \
    barrier_raw();                                         \
    if (DO_WRITE) { WRITESET(S_W, WB) WAIT_LGKM0(); }      \
    barrier_raw();                                         \
    _Pragma("unroll") for (int mi = 0; mi < 6; ++mi)       \
    _Pragma("unroll") for (int nf = 0; nf < 8; ++nf)       \
      acc[mi][nf] = __builtin_amdgcn_mfma_f32_16x16x32_bf16(af[mi], bf[nf], acc[mi][nf], 0, 0, 0); }

#define TILE_PRELUDE                                       \
  const int tid = threadIdx.x, lane = tid & 63, wid = tid >> 6; \
  const int m = lane >> 4, c = lane & 15;                  \
  const int wr = wid & 1, wc = wid >> 1;                   \
  const bool doA = (tid < 192);                            \
  const int arow = min(tid, 191);                          \
  const int asw = arow & 3;                                \
  const int adst0 = arow * 64 + (((0) ^ asw) << 4);        \
  const int adst1 = arow * 64 + (((1) ^ asw) << 4);        \
  const int adst2 = arow * 64 + (((2) ^ asw) << 4);        \
  const int adst3 = arow * 64 + (((3) ^ asw) << 4);        \
  const int bdst = 12288 + (wid * 4) * 1024                \
      + (((lane * 4) ^ ((wid & 1) << 4))) * 4;             \
  int aoffs[6];                                            \
  _Pragma("unroll") for (int mi = 0; mi < 6; ++mi)         \
    aoffs[mi] = (wr * 96 + mi * 16 + c) * 64 + ((m ^ (c & 3)) << 4); \
  int boffs[8];                                            \
  _Pragma("unroll") for (int nf = 0; nf < 8; ++nf)         \
    boffs[nf] = 12288 + (m * 4) * 1024                     \
        + ((wc * 128 + nf * 16 + c) ^ ((m & 1) << 4)) * 4;

// ======== gateup: BM=192, BN=256, item=(rowgroup, mat, nc) = 384 ========
__global__ __launch_bounds__(256, 2) void gateup_kernel(
    const __hip_bfloat16* __restrict__ Xb, const float* __restrict__ WG,
    const float* __restrict__ WU, const int* __restrict__ cnt,
    const int* __restrict__ offs, const int* __restrict__ tokl,
    __hip_bfloat16* __restrict__ Gr, __hip_bfloat16* __restrict__ Ur,
    const int* __restrict__ qm, const int* __restrict__ rgl) {
  __shared__ __align__(16) char sL[2 * BUFSZ];
  TILE_PRELUDE
  const int itot = qm[2] * 6;

  for (int it = blockIdx.x; it < itot; it += 384) {
    const int rg = rgl[it / 6];
    const int rem = it % 6;
    const int mat = rem / 3, nc = rem % 3;
    const int e = rg >> 4, ti = rg & 15;
    const int ne = cnt[e];
    const int nrows = min(192, ne - ti * 192);
    const int nb = nc * 256;
    const int cbase = offs[e] + ti * 192;
    const int tbase = e * T_TOK + ti * 192;

    const short* pap = (const short*)Xb
        + (size_t)tokl[tbase + min(arow, nrows - 1)] * HDIM;
    const float* pbp = (mat ? WU : WG) + (size_t)e * HDIM * IDIM
        + (size_t)(wid * 8) * IDIM + nb + lane * 4;

    f32x4 acc[6][8];
#pragma unroll
    for (int i = 0; i < 6; ++i)
#pragma unroll
      for (int nf = 0; nf < 8; ++nf)
#pragma unroll
        for (int r = 0; r < 4; ++r) acc[i][nf][r] = 0.f;

    int4  xa0_E{}, xa1_E{}, xa2_E{}, xa3_E{};
    int4  xa0_O{}, xa1_O{}, xa2_O{}, xa3_O{};
    f32x4 v0_E{}, v1_E{}, v2_E{}, v3_E{}, v4_E{}, v5_E{}, v6_E{}, v7_E{};
    f32x4 v0_O{}, v1_O{}, v2_O{}, v3_O{}, v4_O{}, v5_O{}, v6_O{}, v7_O{};

    LOADSET(E, IDIM)           // tile 0
    LOADSET(O, IDIM)           // tile 1
    WRITESET(E, 0)
    WAIT_LGKM0();
    barrier_raw();
    for (int p = 0; p < 31; ++p) {           // t = 0..61
      STEP(E, O, 0, 1, IDIM, true, true)
      STEP(O, E, 1, 0, IDIM, true, true)
    }
    STEP(E, O, 0, 1, IDIM, false, true)      // t = 62
    STEP(O, E, 1, 0, IDIM, false, false)     // t = 63

    // epilogue: raw GEMM result -> Gr or Ur (bf16, compact rows)
    __hip_bfloat16* Outb = mat ? Ur : Gr;
#pragma unroll
    for (int mi = 0; mi < 6; ++mi) {
      const int rb = wr * 96 + mi * 16 + m * 4;
#pragma unroll
      for (int nf = 0; nf < 8; ++nf) {
        const int colg = nb + wc * 128 + nf * 16 + c;
#pragma unroll
        for (int r = 0; r < 4; ++r) {
          const int row = rb + r;
          if (row < nrows)
            Outb[(size_t)(cbase + row) * IDIM + colg] = __float2bfloat16(acc[mi][nf][r]);
        }
      }
    }
    barrier_raw();
  }
}

// ---------------- combine: h = silu(g) * u * wt (in-place over Gr) --------
__global__ __launch_bounds__(256) void combine_kernel(
    __hip_bfloat16* __restrict__ Gr, const __hip_bfloat16* __restrict__ Ur,
    const int* __restrict__ cnt, const int* __restrict__ offs,
    const float* __restrict__ wtl) {
  const int e = blockIdx.y, rc = blockIdx.x;
  const int ne = cnt[e];
  const int r = rc * 32 + (threadIdx.x >> 3);
  if (r >= ne) return;
  const float wt = wtl[e * T_TOK + r];
  const size_t rowb = (size_t)(offs[e] + r) * IDIM;
#pragma unroll
  for (int k = 0; k < 12; ++k) {
    const int col = (threadIdx.x & 7) * 8 + k * 64;
    union { short h[8]; int4 q; } g, u, o;
    g.q = *(const int4*)((const char*)Gr + (rowb + col) * 2);
    u.q = *(const int4*)((const char*)Ur + (rowb + col) * 2);
#pragma unroll
    for (int j = 0; j < 8; ++j) {
      union { short s; __hip_bfloat16 b; } cg, cu;
      cg.s = g.h[j]; cu.s = u.h[j];
      const float gf = __bfloat162float(cg.b);
      const float uf = __bfloat162float(cu.b);
      o.h[j] = f2bf((gf / (1.f + __expf(-gf))) * uf * wt);
    }
    *(int4*)((char*)Gr + (rowb + col) * 2) = o.q;
  }
}

// ============ down: BM=192, BN=256, item=(rowgroup, hc of 8) = 512 ========
__global__ __launch_bounds__(256, 2) void down_kernel(
    const __hip_bfloat16* __restrict__ Hh, const float* __restrict__ WD,
    const int* __restrict__ cnt, const int* __restrict__ offs,
    const int* __restrict__ tokl, float* __restrict__ Out,
    const int* __restrict__ qm, const int* __restrict__ rgl) {
  __shared__ __align__(16) char sL[2 * BUFSZ];
  TILE_PRELUDE
  const int itot = qm[2] * 8;

  for (int it = blockIdx.x; it < itot; it += 512) {
    const int rg = rgl[it >> 3];
    const int hc = it & 7;
    const int e = rg >> 4, ti = rg & 15;
    const int ne = cnt[e];
    const int nrows = min(192, ne - ti * 192);
    const int hb = hc * 256;
    const int cbase = offs[e] + ti * 192;
    const int tbase = e * T_TOK + ti * 192;

    const short* pap = (const short*)Hh
        + (size_t)(cbase + min(arow, nrows - 1)) * IDIM;
    const float* pbp = WD + (size_t)e * IDIM * HDIM
        + (size_t)(wid * 8) * HDIM + hb + lane * 4;

    f32x4 acc[6][8];
#pragma unroll
    for (int i = 0; i < 6; ++i)
#pragma unroll
      for (int nf = 0; nf < 8; ++nf)
#pragma unroll
        for (int r = 0; r < 4; ++r) acc[i][nf][r] = 0.f;

    int4  xa0_E{}, xa1_E{}, xa2_E{}, xa3_E{};
    int4  xa0_O{}, xa1_O{}, xa2_O{}, xa3_O{};
    f32x4 v0_E{}, v1_E{}, v2_E{}, v3_E{}, v4_E{}, v5_E{}, v6_E{}, v7_E{};
    f32x4 v0_O{}, v1_O{}, v2_O{}, v3_O{}, v4_O{}, v5_O{}, v6_O{}, v7_O{};

    LOADSET(E, HDIM)           // tile 0
    LOADSET(O, HDIM)           // tile 1
    WRITESET(E, 0)
    WAIT_LGKM0();
    barrier_raw();
    for (int p = 0; p < 11; ++p) {           // t = 0..21
      STEP(E, O, 0, 1, HDIM, true, true)
      STEP(O, E, 1, 0, HDIM, true, true)
    }
    STEP(E, O, 0, 1, HDIM, false, true)      // t = 22
    STEP(O, E, 1, 0, HDIM, false, false)     // t = 23

    // epilogue: fp32 atomic scatter into Out
#pragma unroll
    for (int mi = 0; mi < 6; ++mi) {
      const int rb = wr * 96 + mi * 16 + m * 4;
#pragma unroll
      for (int r = 0; r < 4; ++r) {
        const int row = rb + r;
        if (row < nrows) {
          const int tok = tokl[tbase + row];
          float* op = Out + (size_t)tok * HDIM + hb + wc * 128 + c;
#pragma unroll
          for (int nf = 0; nf < 8; ++nf)
            atomicAdd(op + nf * 16, acc[mi][nf][r]);
        }
      }
    }
    barrier_raw();
  }
}

extern "C" void kernel_launch(void* const* d_in, const int* in_sizes, int n_in,
                              void* d_out, int out_size, void* d_ws, size_t ws_size,
                              hipStream_t stream) {
  (void)in_sizes; (void)n_in; (void)ws_size;
  const float* X  = (const float*)d_in[0];
  const float* GW = (const float*)d_in[1];
  const float* WG = (const float*)d_in[2];
  const float* WU = (const float*)d_in[3];
  const float* WD = (const float*)d_in[4];
  float* Out = (float*)d_out;
  char* ws = (char*)d_ws;

  __hip_bfloat16* Xb = (__hip_bfloat16*)(ws + XBF_OFF);
  int*   cnt  = (int*)(ws + CNT_OFF);
  int*   offs = (int*)(ws + OFF_OFF);
  int*   qm   = (int*)(ws + QM_OFF);
  int*   rgl  = (int*)(ws + RGL_OFF);
  int*   tokl = (int*)(ws + TOK_OFF);
  float* wtl  = (float*)(ws + WT_OFF);
  __hip_bfloat16* Gr = (__hip_bfloat16*)(ws + G_OFF);
  __hip_bfloat16* Ur = (__hip_bfloat16*)(ws + U_OFF);

  hipMemsetAsync(ws + CNT_OFF, 0, 1024, stream);  // cnt + offs + qm
  hipMemsetAsync(d_out, 0, (size_t)out_size * sizeof(float), stream);

  router_kernel<<<T_TOK, 256, 0, stream>>>(X, GW, Xb, cnt, tokl, wtl);
  scan_kernel<<<1, 64, 0, stream>>>(cnt, offs, rgl, qm);
  gateup_kernel<<<384, 256, 0, stream>>>(Xb, WG, WU, cnt, offs, tokl, Gr, Ur, qm, rgl);
  combine_kernel<<<dim3(16, 64), 256, 0, stream>>>(Gr, Ur, cnt, offs, wtl);
  down_kernel<<<512, 256, 0, stream>>>(Gr, WD, cnt, offs, tokl, Out, qm, rgl);
}

// Round 14
// 582.022 us; speedup vs baseline: 3.2353x; 3.2353x over previous
//
#include <hip/hip_runtime.h>
#include <hip/hip_bf16.h>
#include <cstddef>
#include <cstdint>

#define T_TOK 1024
#define HDIM  2048
#define NEXP  64
#define IDIM  768
#define TOPK  8

using f32x4 = __attribute__((ext_vector_type(4))) float;
using s16x8 = __attribute__((ext_vector_type(8))) short;

// ---- workspace layout (bytes) ----
static constexpr size_t XBF_OFF = 0;                                   // bf16 X: 4 MiB
static constexpr size_t CNT_OFF = (size_t)T_TOK * HDIM * 2;            // 64 ints
static constexpr size_t OFF_OFF = CNT_OFF + 256;                       // 65 ints
static constexpr size_t QM_OFF  = CNT_OFF + 768;                       // q_gu, q_dn, nrg
static constexpr size_t RGL_OFF = CNT_OFF + 1024;                      // rowgroup list
static constexpr size_t TOK_OFF = CNT_OFF + 4096;                      // 64*1024 ints
static constexpr size_t WT_OFF  = TOK_OFF + (size_t)NEXP * T_TOK * 4;  // 64*1024 floats
static constexpr size_t G_OFF   = WT_OFF  + (size_t)NEXP * T_TOK * 4;  // 8192*768 bf16 (g -> h)
static constexpr size_t U_OFF   = G_OFF   + (size_t)8192 * IDIM * 2;   // 8192*768 bf16 (u)

__device__ __forceinline__ short f2bf(float f) {
  union { __hip_bfloat16 b; short s; } u;
  u.b = __float2bfloat16(f);
  return u.s;
}
__device__ __forceinline__ uint32_t pk2(float lo, float hi) {
  return ((uint32_t)(uint16_t)f2bf(hi) << 16) | (uint16_t)f2bf(lo);
}
__device__ __forceinline__ void barrier_raw() {
  asm volatile("" ::: "memory");
  __builtin_amdgcn_s_barrier();
  asm volatile("" ::: "memory");
}
#define WAIT_LGKM0() asm volatile("s_waitcnt lgkmcnt(0)" ::: "memory")

// ---------------- router (+ fused fp32->bf16 convert of X) ----------------
__global__ __launch_bounds__(256) void router_kernel(
    const float* __restrict__ X, const float* __restrict__ GW,
    __hip_bfloat16* __restrict__ Xb,
    int* __restrict__ cnt, int* __restrict__ tokl, float* __restrict__ wtl) {
  __shared__ float xs[HDIM];
  __shared__ float lg[NEXP];
  const int t = blockIdx.x;
  const int tid = threadIdx.x;
  const f32x4* xr = (const f32x4*)(X + (size_t)t * HDIM);
#pragma unroll
  for (int i = 0; i < 2; ++i) {
    f32x4 v = xr[tid + i * 256];
    *(f32x4*)&xs[(tid + i * 256) * 4] = v;
  }
  __syncthreads();
  {
    union { short h[8]; int4 q; } u;
#pragma unroll
    for (int j = 0; j < 8; ++j) u.h[j] = f2bf(xs[tid * 8 + j]);
    *(int4*)((char*)Xb + ((size_t)t * HDIM + tid * 8) * 2) = u.q;
  }
  const int wid = tid >> 6, lane = tid & 63;
  for (int ee = 0; ee < 16; ++ee) {
    const int e = wid * 16 + ee;
    const float* g = GW + (size_t)e * HDIM;
    float acc = 0.f;
    for (int i = lane; i < HDIM; i += 64) acc += xs[i] * g[i];
#pragma unroll
    for (int s = 32; s; s >>= 1) acc += __shfl_xor(acc, s);
    if (lane == 0) lg[e] = acc;
  }
  __syncthreads();
  if (tid < 64) {
    const float v = lg[tid];
    float m = v;
#pragma unroll
    for (int s = 32; s; s >>= 1) m = fmaxf(m, __shfl_xor(m, s));
    const float p = expf(v - m);
    float den = p;
#pragma unroll
    for (int s = 32; s; s >>= 1) den += __shfl_xor(den, s);
    float work = p / den;
    float my_v = 0.f; int my_e = 0;
    float topsum = 0.f;
#pragma unroll
    for (int k = 0; k < TOPK; ++k) {
      float mv = work;
#pragma unroll
      for (int s = 32; s; s >>= 1) mv = fmaxf(mv, __shfl_xor(mv, s));
      unsigned long long ball = __ballot(work == mv);
      const int idx = __ffsll(ball) - 1;   // lowest index on ties (matches lax.top_k)
      topsum += mv;
      if (tid == k) { my_v = mv; my_e = idx; }
      if (tid == idx) work = -1.f;
    }
    if (tid < TOPK) {
      const float w = my_v / topsum;
      const int slot = atomicAdd(&cnt[my_e], 1);
      tokl[my_e * T_TOK + slot] = t;
      wtl[my_e * T_TOK + slot] = w;
    }
  }
}

// ---------------- prefix scan + rowgroup list (BM=160) ----------------
__global__ void scan_kernel(const int* __restrict__ cnt, int* __restrict__ offs,
                            int* __restrict__ rgl, int* __restrict__ qm) {
  if (threadIdx.x == 0) {
    int a = 0, nrg = 0;
    for (int e = 0; e < NEXP; ++e) {
      offs[e] = a;
      const int ne = cnt[e];
      a += ne;
      for (int t = 0; t * 160 < ne; ++t) rgl[nrg++] = (e << 4) | t;
    }
    offs[NEXP] = a;
    qm[2] = nrg;
  }
}

// ======================= unified tile machinery =======================
// 256 thr / 4 waves; tile: A 160rows x 32k bf16 (10KB), B 32k x 128n
// fp32 -> bf16 (8KB). Buffer = 18432B, double-buffered (36864). Wave
// grid 2x2 (wr: 80 rows, wc: 64 cols) -> acc[5][4] f32x4 = 80 regs.
// A: one 64B row per thread (tid<160), chunk XOR row&3 swizzle (R13-
// verified). B: 8 rows/wave as 512B float2 runs, kp-paired pk2 with
// kp>>2 XOR swizzle (R10-verified). E/O named-set reg staging (R8).
#define BUFSZ 18432

#define LOADA_(S)                                          \
    xa0_##S = *(const int4*)pap;                           \
    xa1_##S = *(const int4*)(pap + 8);                     \
    xa2_##S = *(const int4*)(pap + 16);                    \
    xa3_##S = *(const int4*)(pap + 24);                    \
    pap += 32;
#define LOADB_(S, LD)                                      \
    v0_##S = *(const float2*)(pbp);                        \
    v1_##S = *(const float2*)(pbp + (LD));                 \
    v2_##S = *(const float2*)(pbp + 2 * (LD));             \
    v3_##S = *(const float2*)(pbp + 3 * (LD));             \
    v4_##S = *(const float2*)(pbp + 4 * (LD));             \
    v5_##S = *(const float2*)(pbp + 5 * (LD));             \
    v6_##S = *(const float2*)(pbp + 6 * (LD));             \
    v7_##S = *(const float2*)(pbp + 7 * (LD));             \
    pbp += (size_t)32 * (LD);
#define LOADSET(S, LD) { if (doA) { LOADA_(S) } LOADB_(S, LD) }

#define WRITESET(S, BUF) {                                 \
    char* base_ = sL + (BUF) * BUFSZ;                      \
    if (doA) {                                             \
      *(int4*)(base_ + adst0) = xa0_##S;                   \
      *(int4*)(base_ + adst1) = xa1_##S;                   \
      *(int4*)(base_ + adst2) = xa2_##S;                   \
      *(int4*)(base_ + adst3) = xa3_##S;                   \
    }                                                      \
    uint2 w_;                                              \
    w_.x = pk2(v0_##S.x, v1_##S.x); w_.y = pk2(v0_##S.y, v1_##S.y); \
    *(uint2*)(base_ + bdst) = w_;                          \
    w_.x = pk2(v2_##S.x, v3_##S.x); w_.y = pk2(v2_##S.y, v3_##S.y); \
    *(uint2*)(base_ + bdst + 512) = w_;                    \
    w_.x = pk2(v4_##S.x, v5_##S.x); w_.y = pk2(v4_##S.y, v5_##S.y); \
    *(uint2*)(base_ + bdst + 1024) = w_;                   \
    w_.x = pk2(v6_##S.x, v7_##S.x); w_.y = pk2(v6_##S.y, v7_##S.y); \
    *(uint2*)(base_ + bdst + 1536) = w_; }

#define STEP(S_L, S_W, RB, WB, LD, DO_LOAD, DO_WRITE) {    \
    if (DO_LOAD) LOADSET(S_L, LD)                          \
    const char* bb_ = sL + (RB) * BUFSZ;                   \
    s16x8 af[5];                                           \
    _Pragma("unroll") for (int mi = 0; mi < 5; ++mi)       \
      af[mi] = *(const s16x8*)(bb_ + aoffs[mi]);           \
    s16x8 bf[4];                                           \
    _Pragma("unroll") for (int nf = 0; nf < 4; ++nf) {     \
      const char* p_ = bb_ + boffs[nf];                    \
      union { uint32_t u[4]; s16x8 v; } w_;                \
      w_.u[0] = *(const uint32_t*)p_;                      \
      w_.u[1] = *(const uint32_t*)(p_ + 512);              \
      w_.u[2] = *(const uint32_t*)(p_ + 1024);             \
      w_.u[3] = *(const uint32_t*)(p_ + 1536);             \
      bf[nf] = w_.v; }                                     \
    WAIT_LGKM0();                                          \
    barrier_raw();                                         \
    if (DO_WRITE) { WRITESET(S_W, WB) WAIT_LGKM0(); }      \
    barrier_raw();                                         \
    _Pragma("unroll") for (int mi = 0; mi < 5; ++mi)       \
    _Pragma("unroll") for (int nf = 0; nf < 4; ++nf)       \
      acc[mi][nf] = __builtin_amdgcn_mfma_f32_16x16x32_bf16(af[mi], bf[nf], acc[mi][nf], 0, 0, 0); }

#define TILE_PRELUDE                                       \
  const int tid = threadIdx.x, lane = tid & 63, wid = tid >> 6; \
  const int m = lane >> 4, c = lane & 15;                  \
  const int wr = wid & 1, wc = wid >> 1;                   \
  const bool doA = (tid < 160);                            \
  const int arow = min(tid, 159);                          \
  const int asw = arow & 3;                                \
  const int adst0 = arow * 64 + (((0) ^ asw) << 4);        \
  const int adst1 = arow * 64 + (((1) ^ asw) << 4);        \
  const int adst2 = arow * 64 + (((2) ^ asw) << 4);        \
  const int adst3 = arow * 64 + (((3) ^ asw) << 4);        \
  const int bdst = 10240 + (wid * 4) * 512                 \
      + (((lane * 2) ^ ((wid & 1) << 4))) * 4;             \
  int aoffs[5];                                            \
  _Pragma("unroll") for (int mi = 0; mi < 5; ++mi)         \
    aoffs[mi] = (wr * 80 + mi * 16 + c) * 64 + ((m ^ (c & 3)) << 4); \
  int boffs[4];                                            \
  _Pragma("unroll") for (int nf = 0; nf < 4; ++nf)         \
    boffs[nf] = 10240 + (m * 4) * 512                      \
        + ((wc * 64 + nf * 16 + c) ^ ((m & 1) << 4)) * 4;

// ==== gateup: BM=160, BN=128, item=(rowgroup, mat, nc of 6) ~= 768+ ====
__global__ __launch_bounds__(256, 2) void gateup_kernel(
    const __hip_bfloat16* __restrict__ Xb, const float* __restrict__ WG,
    const float* __restrict__ WU, const int* __restrict__ cnt,
    const int* __restrict__ offs, const int* __restrict__ tokl,
    __hip_bfloat16* __restrict__ Gr, __hip_bfloat16* __restrict__ Ur,
    int* __restrict__ qm, const int* __restrict__ rgl) {
  __shared__ __align__(16) char sL[2 * BUFSZ];
  __shared__ int sItem;
  TILE_PRELUDE
  const int itot = qm[2] * 12;

  for (;;) {
    __syncthreads();
    if (tid == 0) sItem = atomicAdd(&qm[0], 1);
    __syncthreads();
    const int it = sItem;
    if (it >= itot) break;
    const int rg = rgl[it / 12];
    const int rem = it % 12;
    const int mat = rem / 6, nc = rem % 6;
    const int e = rg >> 4, ti = rg & 15;
    const int ne = cnt[e];
    const int nrows = min(160, ne - ti * 160);
    const int nb = nc * 128;
    const int cbase = offs[e] + ti * 160;
    const int tbase = e * T_TOK + ti * 160;

    const short* pap = (const short*)Xb
        + (size_t)tokl[tbase + min(arow, nrows - 1)] * HDIM;
    const float* pbp = (mat ? WU : WG) + (size_t)e * HDIM * IDIM
        + (size_t)(wid * 8) * IDIM + nb + lane * 2;

    f32x4 acc[5][4];
#pragma unroll
    for (int i = 0; i < 5; ++i)
#pragma unroll
      for (int nf = 0; nf < 4; ++nf)
#pragma unroll
        for (int r = 0; r < 4; ++r) acc[i][nf][r] = 0.f;

    int4  xa0_E{}, xa1_E{}, xa2_E{}, xa3_E{};
    int4  xa0_O{}, xa1_O{}, xa2_O{}, xa3_O{};
    float2 v0_E{}, v1_E{}, v2_E{}, v3_E{}, v4_E{}, v5_E{}, v6_E{}, v7_E{};
    float2 v0_O{}, v1_O{}, v2_O{}, v3_O{}, v4_O{}, v5_O{}, v6_O{}, v7_O{};

    LOADSET(E, IDIM)           // tile 0
    LOADSET(O, IDIM)           // tile 1
    WRITESET(E, 0)
    WAIT_LGKM0();
    barrier_raw();
    for (int p = 0; p < 31; ++p) {           // t = 0..61
      STEP(E, O, 0, 1, IDIM, true, true)
      STEP(O, E, 1, 0, IDIM, true, true)
    }
    STEP(E, O, 0, 1, IDIM, false, true)      // t = 62
    STEP(O, E, 1, 0, IDIM, false, false)     // t = 63

    // epilogue: raw GEMM result -> Gr or Ur (bf16, compact rows)
    __hip_bfloat16* Outb = mat ? Ur : Gr;
#pragma unroll
    for (int mi = 0; mi < 5; ++mi) {
      const int rb = wr * 80 + mi * 16 + m * 4;
#pragma unroll
      for (int nf = 0; nf < 4; ++nf) {
        const int colg = nb + wc * 64 + nf * 16 + c;
#pragma unroll
        for (int r = 0; r < 4; ++r) {
          const int row = rb + r;
          if (row < nrows)
            Outb[(size_t)(cbase + row) * IDIM + colg] = __float2bfloat16(acc[mi][nf][r]);
        }
      }
    }
  }
}

// ---------------- combine: h = silu(g) * u * wt (in-place over Gr) --------
__global__ __launch_bounds__(256) void combine_kernel(
    __hip_bfloat16* __restrict__ Gr, const __hip_bfloat16* __restrict__ Ur,
    const int* __restrict__ cnt, const int* __restrict__ offs,
    const float* __restrict__ wtl) {
  const int e = blockIdx.y, rc = blockIdx.x;
  const int ne = cnt[e];
  const int r = rc * 32 + (threadIdx.x >> 3);
  if (r >= ne) return;
  const float wt = wtl[e * T_TOK + r];
  const size_t rowb = (size_t)(offs[e] + r) * IDIM;
#pragma unroll
  for (int k = 0; k < 12; ++k) {
    const int col = (threadIdx.x & 7) * 8 + k * 64;
    union { short h[8]; int4 q; } g, u, o;
    g.q = *(const int4*)((const char*)Gr + (rowb + col) * 2);
    u.q = *(const int4*)((const char*)Ur + (rowb + col) * 2);
#pragma unroll
    for (int j = 0; j < 8; ++j) {
      union { short s; __hip_bfloat16 b; } cg, cu;
      cg.s = g.h[j]; cu.s = u.h[j];
      const float gf = __bfloat162float(cg.b);
      const float uf = __bfloat162float(cu.b);
      o.h[j] = f2bf((gf / (1.f + __expf(-gf))) * uf * wt);
    }
    *(int4*)((char*)Gr + (rowb + col) * 2) = o.q;
  }
}

// ======== down: BM=160, BN=128, item=(rowgroup, hc of 16) ~= 1024+ ========
__global__ __launch_bounds__(256, 2) void down_kernel(
    const __hip_bfloat16* __restrict__ Hh, const float* __restrict__ WD,
    const int* __restrict__ cnt, const int* __restrict__ offs,
    const int* __restrict__ tokl, float* __restrict__ Out,
    int* __restrict__ qm, const int* __restrict__ rgl) {
  __shared__ __align__(16) char sL[2 * BUFSZ];
  __shared__ int sItem;
  TILE_PRELUDE
  const int itot = qm[2] * 16;

  for (;;) {
    __syncthreads();
    if (tid == 0) sItem = atomicAdd(&qm[1], 1);
    __syncthreads();
    const int it = sItem;
    if (it >= itot) break;
    const int rg = rgl[it >> 4];
    const int hc = it & 15;
    const int e = rg >> 4, ti = rg & 15;
    const int ne = cnt[e];
    const int nrows = min(160, ne - ti * 160);
    const int hb = hc * 128;
    const int cbase = offs[e] + ti * 160;
    const int tbase = e * T_TOK + ti * 160;

    const short* pap = (const short*)Hh
        + (size_t)(cbase + min(arow, nrows - 1)) * IDIM;
    const float* pbp = WD + (size_t)e * IDIM * HDIM
        + (size_t)(wid * 8) * HDIM + hb + lane * 2;

    f32x4 acc[5][4];
#pragma unroll
    for (int i = 0; i < 5; ++i)
#pragma unroll
      for (int nf = 0; nf < 4; ++nf)
#pragma unroll
        for (int r = 0; r < 4; ++r) acc[i][nf][r] = 0.f;

    int4  xa0_E{}, xa1_E{}, xa2_E{}, xa3_E{};
    int4  xa0_O{}, xa1_O{}, xa2_O{}, xa3_O{};
    float2 v0_E{}, v1_E{}, v2_E{}, v3_E{}, v4_E{}, v5_E{}, v6_E{}, v7_E{};
    float2 v0_O{}, v1_O{}, v2_O{}, v3_O{}, v4_O{}, v5_O{}, v6_O{}, v7_O{};

    LOADSET(E, HDIM)           // tile 0
    LOADSET(O, HDIM)           // tile 1
    WRITESET(E, 0)
    WAIT_LGKM0();
    barrier_raw();
    for (int p = 0; p < 11; ++p) {           // t = 0..21
      STEP(E, O, 0, 1, HDIM, true, true)
      STEP(O, E, 1, 0, HDIM, true, true)
    }
    STEP(E, O, 0, 1, HDIM, false, true)      // t = 22
    STEP(O, E, 1, 0, HDIM, false, false)     // t = 23

    // epilogue: fp32 atomic scatter into Out
#pragma unroll
    for (int mi = 0; mi < 5; ++mi) {
      const int rb = wr * 80 + mi * 16 + m * 4;
#pragma unroll
      for (int r = 0; r < 4; ++r) {
        const int row = rb + r;
        if (row < nrows) {
          const int tok = tokl[tbase + row];
          float* op = Out + (size_t)tok * HDIM + hb + wc * 64 + c;
#pragma unroll
          for (int nf = 0; nf < 4; ++nf)
            atomicAdd(op + nf * 16, acc[mi][nf][r]);
        }
      }
    }
  }
}

extern "C" void kernel_launch(void* const* d_in, const int* in_sizes, int n_in,
                              void* d_out, int out_size, void* d_ws, size_t ws_size,
                              hipStream_t stream) {
  (void)in_sizes; (void)n_in; (void)ws_size;
  const float* X  = (const float*)d_in[0];
  const float* GW = (const float*)d_in[1];
  const float* WG = (const float*)d_in[2];
  const float* WU = (const float*)d_in[3];
  const float* WD = (const float*)d_in[4];
  float* Out = (float*)d_out;
  char* ws = (char*)d_ws;

  __hip_bfloat16* Xb = (__hip_bfloat16*)(ws + XBF_OFF);
  int*   cnt  = (int*)(ws + CNT_OFF);
  int*   offs = (int*)(ws + OFF_OFF);
  int*   qm   = (int*)(ws + QM_OFF);
  int*   rgl  = (int*)(ws + RGL_OFF);
  int*   tokl = (int*)(ws + TOK_OFF);
  float* wtl  = (float*)(ws + WT_OFF);
  __hip_bfloat16* Gr = (__hip_bfloat16*)(ws + G_OFF);
  __hip_bfloat16* Ur = (__hip_bfloat16*)(ws + U_OFF);

  hipMemsetAsync(ws + CNT_OFF, 0, 1024, stream);  // cnt + offs + qm
  hipMemsetAsync(d_out, 0, (size_t)out_size * sizeof(float), stream);

  router_kernel<<<T_TOK, 256, 0, stream>>>(X, GW, Xb, cnt, tokl, wtl);
  scan_kernel<<<1, 64, 0, stream>>>(cnt, offs, rgl, qm);
  gateup_kernel<<<512, 256, 0, stream>>>(Xb, WG, WU, cnt, offs, tokl, Gr, Ur, qm, rgl);
  combine_kernel<<<dim3(16, 64), 256, 0, stream>>>(Gr, Ur, cnt, offs, wtl);
  down_kernel<<<512, 256, 0, stream>>>(Gr, WD, cnt, offs, tokl, Out, qm, rgl);
}